// Round 1
// baseline (5824.125 us; speedup 1.0000x reference)
//
#include <hip/hip_runtime.h>

#define HDIM 1024
// last_layer batch stride (rows*H)
#define LLBS 1048576L   // 1024*1024
#define OPTBS 262144L   // 256*1024

struct FCSrc { const float* s0; const float* s1; long s0bs; long s1bs; int op; int pad; };
struct FCArgs {
  FCSrc src[7];
  int nblk; int act;            // act: 0=tanh, 1=relu, 2=sigmoid-lerp
  const float* W;               // (1024, nblk*1024) row-major (out, in)
  const float* bias;            // (1024)
  float* out; long outbs;       // (b, 256, 1024)
  const float* e0; const float* e1; long e0bs; long e1bs;  // lerp sources
};

// ---------------- rowdot: out[b*R+r] = dot(X(b,r,:), w) ----------------
__global__ __launch_bounds__(256)
void rowdot_kernel(const float* __restrict__ base, long bs, int R,
                   const float* __restrict__ w, float* __restrict__ out)
{
  const int row  = blockIdx.x * 4 + (threadIdx.x >> 6);
  const int lane = threadIdx.x & 63;
  const int b = row / R, r = row - b * R;
  const float* p = base + (long)b * bs + (long)r * HDIM;
  float s = 0.f;
  #pragma unroll 4
  for (int d = lane; d < HDIM; d += 64) s += p[d] * w[d];
  #pragma unroll
  for (int off = 32; off; off >>= 1) s += __shfl_down(s, off, 64);
  if (lane == 0) out[row] = s;
}

// ---------------- shared gemm tile core (64x64 tile, K-step 16) ----------------
// TRANSB=1: C[i][j] += A[i,k]*B[j,k]*scale[k]   (A: M x K, B: N x K)
// TRANSB=0: C[i][j] += A[i,k]*B[k,j]            (A: M x K, B: K x N)
template<int TRANSB>
__device__ __forceinline__
void gemm_core(float (*As)[68], float (*Bs)[68],
               const float* __restrict__ Ab, int Ars,
               const float* __restrict__ Bb, int Brs,
               int K, const float* __restrict__ scale,
               int i0, int j0, int t, float acc[4][4])
{
  const int lr = t >> 2, lq = (t & 3) << 2;
  const int tx = t & 15, ty = t >> 4;
  for (int k0 = 0; k0 < K; k0 += 16) {
    float4 a4 = *(const float4*)(Ab + (long)(i0 + lr) * Ars + k0 + lq);
    float4 b4;
    int kr = 0, nq = 0;
    if (TRANSB) {
      b4 = *(const float4*)(Bb + (long)(j0 + lr) * Brs + k0 + lq);
      if (scale) {
        b4.x *= scale[k0 + lq + 0]; b4.y *= scale[k0 + lq + 1];
        b4.z *= scale[k0 + lq + 2]; b4.w *= scale[k0 + lq + 3];
      }
    } else {
      kr = t >> 4; nq = (t & 15) << 2;
      b4 = *(const float4*)(Bb + (long)(k0 + kr) * Brs + j0 + nq);
    }
    __syncthreads();
    As[lq + 0][lr] = a4.x; As[lq + 1][lr] = a4.y; As[lq + 2][lr] = a4.z; As[lq + 3][lr] = a4.w;
    if (TRANSB) {
      Bs[lq + 0][lr] = b4.x; Bs[lq + 1][lr] = b4.y; Bs[lq + 2][lr] = b4.z; Bs[lq + 3][lr] = b4.w;
    } else {
      Bs[kr][nq + 0] = b4.x; Bs[kr][nq + 1] = b4.y; Bs[kr][nq + 2] = b4.z; Bs[kr][nq + 3] = b4.w;
    }
    __syncthreads();
    #pragma unroll
    for (int dd = 0; dd < 16; ++dd) {
      const float4 av = *(const float4*)(&As[dd][ty << 2]);
      const float4 bv = *(const float4*)(&Bs[dd][tx << 2]);
      const float a_[4] = {av.x, av.y, av.z, av.w};
      const float b_[4] = {bv.x, bv.y, bv.z, bv.w};
      #pragma unroll
      for (int ii = 0; ii < 4; ++ii)
        #pragma unroll
        for (int jj = 0; jj < 4; ++jj)
          acc[ii][jj] += a_[ii] * b_[jj];
    }
  }
}

// ---------------- generic batched gemm with optional rank-1 epilogue ----------------
template<int TRANSB>
__global__ __launch_bounds__(256)
void gemm_kernel(const float* __restrict__ A, long Abs, int Ars,
                 const float* __restrict__ B, long Bbs, int Brs,
                 int K,
                 const float* __restrict__ scale,
                 const float* __restrict__ ql, long qlbs,
                 const float* __restrict__ kl, long klbs,
                 float* __restrict__ C, long Cbs, int Crs)
{
  __shared__ float As[16][68], Bs[16][68];
  const int b = blockIdx.z;
  const int i0 = blockIdx.y << 6, j0 = blockIdx.x << 6;
  const int t = threadIdx.x;
  float acc[4][4] = {};
  gemm_core<TRANSB>(As, Bs, A + (long)b * Abs, Ars, B + (long)b * Bbs, Brs,
                    K, scale, i0, j0, t, acc);
  const int tx = t & 15, ty = t >> 4;
  float* Cb = C + (long)b * Cbs;
  #pragma unroll
  for (int ii = 0; ii < 4; ++ii) {
    const int i = i0 + (ty << 2) + ii;
    const float qv = ql ? ql[(long)b * qlbs + i] : 0.f;
    const int j = j0 + (tx << 2);
    float4 o;
    o.x = acc[ii][0] + qv + (kl ? kl[(long)b * klbs + j + 0] : 0.f);
    o.y = acc[ii][1] + qv + (kl ? kl[(long)b * klbs + j + 1] : 0.f);
    o.z = acc[ii][2] + qv + (kl ? kl[(long)b * klbs + j + 2] : 0.f);
    o.w = acc[ii][3] + qv + (kl ? kl[(long)b * klbs + j + 3] : 0.f);
    *(float4*)(Cb + (long)i * Crs + j) = o;
  }
}

// ---------------- stage A: all 12 (i,j) pairs batched; z = pair*8 + b8 ----------------
__device__ __forceinline__ void pair_decode(int pair, int& i, int& j) {
  i = pair / 3; const int r = pair - i * 3; j = r + (r >= i ? 1 : 0);
}

__global__ __launch_bounds__(256)
void stageA_logits_kernel(const float* __restrict__ OPT, const float* __restrict__ w3,
                          const float* __restrict__ ql_all, const float* __restrict__ kl_all,
                          float* __restrict__ L)
{
  __shared__ float As[16][68], Bs[16][68];
  const int z = blockIdx.z;
  const int pair = z >> 3, b8 = z & 7;
  int i, j; pair_decode(pair, i, j);
  const int bi = b8 * 4 + i, bj = b8 * 4 + j;
  const int t = threadIdx.x;
  const int i0 = blockIdx.y << 6, j0 = blockIdx.x << 6;
  float acc[4][4] = {};
  gemm_core<1>(As, Bs, OPT + (long)bi * LLBS, HDIM, OPT + (long)bj * LLBS, HDIM,
               HDIM, w3, i0, j0, t, acc);
  const int tx = t & 15, ty = t >> 4;
  const float* qlp = ql_all + bi * 256;
  const float* klp = kl_all + bj * 256;
  float* Cb = L + (long)z * 65536;
  #pragma unroll
  for (int ii = 0; ii < 4; ++ii) {
    const int ir = i0 + (ty << 2) + ii;
    const float qv = qlp[ir];
    const int jc = j0 + (tx << 2);
    float4 o;
    o.x = acc[ii][0] + qv + klp[jc + 0];
    o.y = acc[ii][1] + qv + klp[jc + 1];
    o.z = acc[ii][2] + qv + klp[jc + 2];
    o.w = acc[ii][3] + qv + klp[jc + 3];
    *(float4*)(Cb + (long)ir * 256 + jc) = o;
  }
}

__global__ __launch_bounds__(256)
void stageA_attn_kernel(const float* __restrict__ L, const float* __restrict__ OPT,
                        float* __restrict__ aBuf)
{
  __shared__ float As[16][68], Bs[16][68];
  const int z = blockIdx.z;
  const int pair = z >> 3, b8 = z & 7;
  int i, j; pair_decode(pair, i, j);
  const int bj = b8 * 4 + j;
  const int t = threadIdx.x;
  const int i0 = blockIdx.y << 6, j0 = blockIdx.x << 6;
  float acc[4][4] = {};
  gemm_core<0>(As, Bs, L + (long)z * 65536, 256, OPT + (long)bj * LLBS, HDIM,
               256, nullptr, i0, j0, t, acc);
  const int tx = t & 15, ty = t >> 4;
  float* Cb = aBuf + (long)z * OPTBS;
  #pragma unroll
  for (int ii = 0; ii < 4; ++ii) {
    const int ir = i0 + (ty << 2) + ii;
    const int jc = j0 + (tx << 2);
    float4 o = {acc[ii][0], acc[ii][1], acc[ii][2], acc[ii][3]};
    *(float4*)(Cb + (long)ir * HDIM + jc) = o;
  }
}

// ---------------- fused concat-linear: out = act(bias + sum_blk op(s0,s1) @ W_blk^T) ----------------
__global__ __launch_bounds__(256)
void fused_linear_kernel(FCArgs P)
{
  __shared__ float As[16][68], Ws[16][68];
  const int b = blockIdx.z;
  const int i0 = blockIdx.y << 6, n0 = blockIdx.x << 6;
  const int t = threadIdx.x;
  const int lr = t >> 2, lq = (t & 3) << 2;
  const int tx = t & 15, ty = t >> 4;
  const int Ktot = P.nblk << 10;
  float acc[4][4] = {};
  for (int blk = 0; blk < P.nblk; ++blk) {
    const FCSrc S = P.src[blk];
    const float* p0 = S.s0 + (long)b * S.s0bs + (long)(i0 + lr) * HDIM + lq;
    const float* p1 = (S.op != 0) ? (S.s1 + (long)b * S.s1bs + (long)(i0 + lr) * HDIM + lq) : nullptr;
    const float* pw = P.W + (long)(n0 + lr) * Ktot + (blk << 10) + lq;
    for (int kk = 0; kk < 1024; kk += 16) {
      float4 x = *(const float4*)(p0 + kk);
      if (S.op == 1) {
        const float4 y = *(const float4*)(p1 + kk);
        x.x *= y.x; x.y *= y.y; x.z *= y.z; x.w *= y.w;
      } else if (S.op == 2) {
        const float4 y = *(const float4*)(p1 + kk);
        x.x -= y.x; x.y -= y.y; x.z -= y.z; x.w -= y.w;
      }
      const float4 wv = *(const float4*)(pw + kk);
      __syncthreads();
      As[lq + 0][lr] = x.x;  As[lq + 1][lr] = x.y;  As[lq + 2][lr] = x.z;  As[lq + 3][lr] = x.w;
      Ws[lq + 0][lr] = wv.x; Ws[lq + 1][lr] = wv.y; Ws[lq + 2][lr] = wv.z; Ws[lq + 3][lr] = wv.w;
      __syncthreads();
      #pragma unroll
      for (int dd = 0; dd < 16; ++dd) {
        const float4 av = *(const float4*)(&As[dd][ty << 2]);
        const float4 wv4 = *(const float4*)(&Ws[dd][tx << 2]);
        const float a_[4] = {av.x, av.y, av.z, av.w};
        const float w_[4] = {wv4.x, wv4.y, wv4.z, wv4.w};
        #pragma unroll
        for (int ii = 0; ii < 4; ++ii)
          #pragma unroll
          for (int jj = 0; jj < 4; ++jj)
            acc[ii][jj] += a_[ii] * w_[jj];
      }
    }
  }
  #pragma unroll
  for (int ii = 0; ii < 4; ++ii) {
    const int i = i0 + (ty << 2) + ii;
    const int n = n0 + (tx << 2);
    float4 o;
    o.x = acc[ii][0] + P.bias[n + 0];
    o.y = acc[ii][1] + P.bias[n + 1];
    o.z = acc[ii][2] + P.bias[n + 2];
    o.w = acc[ii][3] + P.bias[n + 3];
    if (P.act == 0) {
      o.x = tanhf(o.x); o.y = tanhf(o.y); o.z = tanhf(o.z); o.w = tanhf(o.w);
    } else if (P.act == 1) {
      o.x = fmaxf(o.x, 0.f); o.y = fmaxf(o.y, 0.f); o.z = fmaxf(o.z, 0.f); o.w = fmaxf(o.w, 0.f);
    } else {
      const float4 e = *(const float4*)(P.e0 + (long)b * P.e0bs + (long)i * HDIM + n);
      const float4 c = *(const float4*)(P.e1 + (long)b * P.e1bs + (long)i * HDIM + n);
      float s;
      s = 1.f / (1.f + __expf(-o.x)); o.x = e.x * s + c.x * (1.f - s);
      s = 1.f / (1.f + __expf(-o.y)); o.y = e.y * s + c.y * (1.f - s);
      s = 1.f / (1.f + __expf(-o.z)); o.z = e.z * s + c.z * (1.f - s);
      s = 1.f / (1.f + __expf(-o.w)); o.w = e.w * s + c.w * (1.f - s);
    }
    *(float4*)(P.out + (long)b * P.outbs + (long)i * HDIM + n) = o;
  }
}

// ---------------- softmax over last dim; one wave per row; rows contiguous ----------------
template<int CNT>
__global__ __launch_bounds__(256)
void softmax_rows_kernel(float* __restrict__ L)
{
  const int row = blockIdx.x * 4 + (threadIdx.x >> 6);
  const int lane = threadIdx.x & 63;
  float* p = L + (long)row * (CNT * 64);
  float v[CNT];
  float m = -3.0e38f;
  #pragma unroll
  for (int u = 0; u < CNT; ++u) { v[u] = p[lane + (u << 6)]; m = fmaxf(m, v[u]); }
  #pragma unroll
  for (int off = 32; off; off >>= 1) m = fmaxf(m, __shfl_xor(m, off, 64));
  float s = 0.f;
  #pragma unroll
  for (int u = 0; u < CNT; ++u) { v[u] = __expf(v[u] - m); s += v[u]; }
  #pragma unroll
  for (int off = 32; off; off >>= 1) s += __shfl_xor(s, off, 64);
  const float inv = 1.f / s;
  #pragma unroll
  for (int u = 0; u < CNT; ++u) p[lane + (u << 6)] = v[u] * inv;
}

// ---------------- softmax over axis 1 (queries); thread per column (coalesced in j) ----------------
__global__ __launch_bounds__(256)
void softmax_cols_kernel(const float* __restrict__ L, float* __restrict__ out, int M, int N)
{
  const int b = blockIdx.y;
  const int j = blockIdx.x * 256 + threadIdx.x;
  const float* p = L + (long)b * M * N + j;
  float* o = out + (long)b * M * N + j;
  float m = -3.0e38f;
  for (int i = 0; i < M; ++i) m = fmaxf(m, p[(long)i * N]);
  float s = 0.f;
  for (int i = 0; i < M; ++i) { const float e = __expf(p[(long)i * N] - m); o[(long)i * N] = e; s += e; }
  const float inv = 1.f / s;
  for (int i = 0; i < M; ++i) o[(long)i * N] *= inv;
}

// ---------------- final masked max over sequence (mask all-true) ----------------
__global__ __launch_bounds__(256)
void colmax_kernel(const float* __restrict__ X, float* __restrict__ out)
{
  const int b = blockIdx.y;
  const int d = blockIdx.x * 256 + threadIdx.x;
  const float* p = X + (long)b * (256 * HDIM) + d;
  float m = -3.0e38f;
  for (int r = 0; r < 256; ++r) m = fmaxf(m, p[r * HDIM]);
  out[b * HDIM + d] = m;
}

extern "C" void kernel_launch(void* const* d_in, const int* in_sizes, int n_in,
                              void* d_out, int out_size, void* d_ws, size_t ws_size,
                              hipStream_t stream)
{
  (void)in_sizes; (void)n_in; (void)out_size; (void)ws_size;
  const float* last   = (const float*)d_in[4];
  const float* ow1    = (const float*)d_in[5];
  const float* ow2    = (const float*)d_in[6];
  const float* ow3    = (const float*)d_in[7];
  const float* dw1    = (const float*)d_in[8];
  const float* dw2    = (const float*)d_in[9];
  const float* dw3    = (const float*)d_in[10];
  const float* sw1    = (const float*)d_in[11];
  const float* sw2    = (const float*)d_in[12];
  const float* sw3    = (const float*)d_in[13];
  const float* comp_w = (const float*)d_in[14];
  const float* comp_b = (const float*)d_in[15];
  const float* gate_w = (const float*)d_in[16];
  const float* gate_b = (const float*)d_in[17];
  const float* attn_w = (const float*)d_in[18];
  const float* attn_b = (const float*)d_in[19];
  const float* self_w = (const float*)d_in[20];
  const float* self_b = (const float*)d_in[21];

  const float* OPT = last + 768 * 1024;   // opt_enc view: (32, 256, H), batch stride LLBS

  float* ws = (float*)d_ws;
  long off = 0;
  auto alloc = [&](long n) { float* p = ws + off; off += n; return p; };
  float* ql_all = alloc(8192);               // (32,256) opt . ow1
  float* kl_all = alloc(8192);               // (32,256) opt . ow2
  float* ql_c   = alloc(8192);               // (32,256) option . dw1
  float* kl_c   = alloc(24576);              // (32,768) doc . dw2
  float* ql_e   = alloc(8192);
  float* kl_e   = alloc(8192);
  float* aBuf   = alloc(12L * 8 * 256 * 1024);   // [pair][b8][256][1024]
  float* L      = alloc(32L * 256 * 768);        // logits scratch (max size; reused A/C/E)
  float* kq     = alloc(32L * 256 * 768);
  float* co_w   = alloc(32L * 256 * 256);
  float* buf1   = alloc(32L * 256 * 1024);       // opt_corr, then attn_a
  float* buf2   = alloc(32L * 256 * 1024);       // option, then sa
  float* buf3   = alloc(32L * 256 * 1024);       // co, then fusion2
  float* buf4   = alloc(32L * 256 * 1024);       // fusion

  // ---- stage A: cross-option attentions (12 pairs batched, z = pair*8 + b8) ----
  rowdot_kernel<<<8192 / 4, 256, 0, stream>>>(OPT, LLBS, 256, ow1, ql_all);
  rowdot_kernel<<<8192 / 4, 256, 0, stream>>>(OPT, LLBS, 256, ow2, kl_all);
  stageA_logits_kernel<<<dim3(4, 4, 96), 256, 0, stream>>>(OPT, ow3, ql_all, kl_all, L);
  softmax_rows_kernel<4><<<(96 * 256) / 4, 256, 0, stream>>>(L);
  stageA_attn_kernel<<<dim3(16, 4, 96), 256, 0, stream>>>(L, OPT, aBuf);

  for (int i = 0; i < 4; ++i) {   // corr_i = tanh(concat(...) @ comp_w^T + comp_b)
    FCArgs P = {};
    const float* cur = OPT + (long)i * LLBS;          // (b8,256,H), b8 stride 4*LLBS
    P.src[0] = {cur, nullptr, 4L * LLBS, 0, 0, 0};
    int m = 0;
    for (int j = 0; j < 4; ++j) {
      if (j == i) continue;
      const float* am = aBuf + (long)(i * 3 + m) * (8L * OPTBS);   // b8 stride OPTBS
      P.src[1 + 2 * m] = {cur, am, 4L * LLBS, OPTBS, 1, 0};  // cur * a
      P.src[2 + 2 * m] = {cur, am, 4L * LLBS, OPTBS, 2, 0};  // cur - a
      ++m;
    }
    P.nblk = 7; P.act = 0; P.W = comp_w; P.bias = comp_b;
    P.out = buf1 + (long)i * OPTBS; P.outbs = 4L * OPTBS;    // opt_corr[b8*4+i]
    fused_linear_kernel<<<dim3(16, 4, 8), 256, 0, stream>>>(P);
  }

  // ---- stage B: gate + lerp -> option (buf2) ----
  {
    FCArgs P = {};
    P.src[0] = {OPT,  nullptr, LLBS,  0, 0, 0};
    P.src[1] = {buf1, nullptr, OPTBS, 0, 0, 0};
    P.nblk = 2; P.act = 2; P.W = gate_w; P.bias = gate_b;
    P.e0 = OPT; P.e0bs = LLBS; P.e1 = buf1; P.e1bs = OPTBS;
    P.out = buf2; P.outbs = OPTBS;
    fused_linear_kernel<<<dim3(16, 4, 32), 256, 0, stream>>>(P);
  }

  // ---- stage C: doc attention (attn + co_attn) ----
  rowdot_kernel<<<8192 / 4, 256, 0, stream>>>(buf2, OPTBS, 256, dw1, ql_c);
  rowdot_kernel<<<24576 / 4, 256, 0, stream>>>(last, LLBS, 768, dw2, kl_c);
  gemm_kernel<1><<<dim3(12, 4, 32), 256, 0, stream>>>(buf2, OPTBS, HDIM, last, LLBS, HDIM, HDIM,
                                                      dw3, ql_c, 256, kl_c, 768, L, 196608, 768);
  softmax_cols_kernel<<<dim3(3, 32), 256, 0, stream>>>(L, kq, 256, 768);
  softmax_rows_kernel<12><<<8192 / 4, 256, 0, stream>>>(L);          // L -> aw
  gemm_kernel<0><<<dim3(16, 4, 32), 256, 0, stream>>>(L, 196608, 768, last, LLBS, HDIM, 768,
                                                      nullptr, nullptr, 0, nullptr, 0, buf1, OPTBS, HDIM);
  gemm_kernel<1><<<dim3(4, 4, 32), 256, 0, stream>>>(L, 196608, 768, kq, 196608, 768, 768,
                                                     nullptr, nullptr, 0, nullptr, 0, co_w, 65536, 256);
  gemm_kernel<0><<<dim3(16, 4, 32), 256, 0, stream>>>(co_w, 65536, 256, buf2, OPTBS, HDIM, 256,
                                                      nullptr, nullptr, 0, nullptr, 0, buf3, OPTBS, HDIM);

  // ---- stage D: fusion = relu([option, a, co] @ attn_w^T + b) -> buf4 ----
  {
    FCArgs P = {};
    P.src[0] = {buf2, nullptr, OPTBS, 0, 0, 0};
    P.src[1] = {buf1, nullptr, OPTBS, 0, 0, 0};
    P.src[2] = {buf3, nullptr, OPTBS, 0, 0, 0};
    P.nblk = 3; P.act = 1; P.W = attn_w; P.bias = attn_b;
    P.out = buf4; P.outbs = OPTBS;
    fused_linear_kernel<<<dim3(16, 4, 32), 256, 0, stream>>>(P);
  }

  // ---- stage E: self-attention on fusion -> sa (buf2) ----
  rowdot_kernel<<<8192 / 4, 256, 0, stream>>>(buf4, OPTBS, 256, sw1, ql_e);
  rowdot_kernel<<<8192 / 4, 256, 0, stream>>>(buf4, OPTBS, 256, sw2, kl_e);
  gemm_kernel<1><<<dim3(4, 4, 32), 256, 0, stream>>>(buf4, OPTBS, HDIM, buf4, OPTBS, HDIM, HDIM,
                                                     sw3, ql_e, 256, kl_e, 256, L, 65536, 256);
  softmax_rows_kernel<4><<<8192 / 4, 256, 0, stream>>>(L);
  gemm_kernel<0><<<dim3(16, 4, 32), 256, 0, stream>>>(L, 65536, 256, buf4, OPTBS, HDIM, 256,
                                                      nullptr, nullptr, 0, nullptr, 0, buf2, OPTBS, HDIM);

  // ---- stage F: fusion2 = relu([fusion, sa, fusion*sa, fusion-sa] @ self_w^T + b) -> buf3 ----
  {
    FCArgs P = {};
    P.src[0] = {buf4, nullptr, OPTBS, 0, 0, 0};
    P.src[1] = {buf2, nullptr, OPTBS, 0, 0, 0};
    P.src[2] = {buf4, buf2, OPTBS, OPTBS, 1, 0};
    P.src[3] = {buf4, buf2, OPTBS, OPTBS, 2, 0};
    P.nblk = 4; P.act = 1; P.W = self_w; P.bias = self_b;
    P.out = buf3; P.outbs = OPTBS;
    fused_linear_kernel<<<dim3(16, 4, 32), 256, 0, stream>>>(P);
  }

  // ---- stage G: out[b, d] = max_r fusion2[b, r, d] ----
  colmax_kernel<<<dim3(4, 32), 256, 0, stream>>>(buf3, (float*)d_out);
}

// Round 2
// 1982.289 us; speedup vs baseline: 2.9381x; 2.9381x over previous
//
#include <hip/hip_runtime.h>

#define HDIM 1024
#define LLBS 1048576L   // 1024*1024
#define OPTBS 262144L   // 256*1024
#define LDSP 40         // padded LDS row length in f16 (80 B): bank-conflict-free frag reads

typedef _Float16 f16;
typedef __attribute__((ext_vector_type(8))) _Float16 f16x8;
typedef __attribute__((ext_vector_type(4))) _Float16 f16x4;
typedef __attribute__((ext_vector_type(4))) float    f32x4;

// ---------------- staging helpers: 128 rows x 32 k, f32 -> f16 into padded LDS ----------------
__device__ __forceinline__ void st16(f16* dst, float4 a, float4 b, float4 c, float4 d) {
  *(f16x8*)dst       = f16x8{(f16)a.x,(f16)a.y,(f16)a.z,(f16)a.w,(f16)b.x,(f16)b.y,(f16)b.z,(f16)b.w};
  *(f16x8*)(dst + 8) = f16x8{(f16)c.x,(f16)c.y,(f16)c.z,(f16)c.w,(f16)d.x,(f16)d.y,(f16)d.z,(f16)d.w};
}

// rows are k-contiguous (row stride rs); src pre-offset to (row0, k0)
__device__ __forceinline__
void stage_rows(f16* __restrict__ sh, const float* __restrict__ src, long rs, int t)
{
  const int row = t >> 1, h = (t & 1) << 4;
  const float4* p = (const float4*)(src + (long)row * rs + h);
  st16(&sh[row * LDSP + h], p[0], p[1], p[2], p[3]);
}

__device__ __forceinline__
void stage_rows_scale(f16* __restrict__ sh, const float* __restrict__ src, long rs,
                      const float* __restrict__ sc, int t)
{
  const int row = t >> 1, h = (t & 1) << 4;
  const float4* p = (const float4*)(src + (long)row * rs + h);
  const float4* s = (const float4*)(sc + h);
  float4 a = p[0], b = p[1], c = p[2], d = p[3];
  const float4 sa = s[0], sb = s[1], sc2 = s[2], sd = s[3];
  a.x*=sa.x; a.y*=sa.y; a.z*=sa.z; a.w*=sa.w;
  b.x*=sb.x; b.y*=sb.y; b.z*=sb.z; b.w*=sb.w;
  c.x*=sc2.x; c.y*=sc2.y; c.z*=sc2.z; c.w*=sc2.w;
  d.x*=sd.x; d.y*=sd.y; d.z*=sd.z; d.w*=sd.w;
  st16(&sh[row * LDSP + h], a, b, c, d);
}

// V-tile transpose staging: src rows are k (stride rs), cols j; store Vt[j][k]
__device__ __forceinline__
void stage_vt(f16* __restrict__ sh, const float* __restrict__ src, long rs, int t)
{
  const int jc = (t & 31) << 2, kg = (t >> 5) << 2;
  const float* p = src + (long)kg * rs + jc;
  const float4 r0 = *(const float4*)p;
  const float4 r1 = *(const float4*)(p + rs);
  const float4 r2 = *(const float4*)(p + 2 * rs);
  const float4 r3 = *(const float4*)(p + 3 * rs);
  *(f16x4*)&sh[(jc + 0) * LDSP + kg] = f16x4{(f16)r0.x,(f16)r1.x,(f16)r2.x,(f16)r3.x};
  *(f16x4*)&sh[(jc + 1) * LDSP + kg] = f16x4{(f16)r0.y,(f16)r1.y,(f16)r2.y,(f16)r3.y};
  *(f16x4*)&sh[(jc + 2) * LDSP + kg] = f16x4{(f16)r0.z,(f16)r1.z,(f16)r2.z,(f16)r3.z};
  *(f16x4*)&sh[(jc + 3) * LDSP + kg] = f16x4{(f16)r0.w,(f16)r1.w,(f16)r2.w,(f16)r3.w};
}

// ---------------- MFMA consume: 4 waves in 2x2, each 64x64 via 4x4 of 16x16x32 ----------------
__device__ __forceinline__
void mfma_step(const f16* __restrict__ Ash, const f16* __restrict__ Bsh, int t, f32x4 acc[4][4])
{
  const int lane = t & 63, wid = t >> 6;
  const int wm = (wid >> 1) << 6, wn = (wid & 1) << 6;
  const int r = lane & 15, kg = (lane >> 4) << 3;
  f16x8 af[4], bf[4];
  #pragma unroll
  for (int m = 0; m < 4; ++m) af[m] = *(const f16x8*)&Ash[(wm + m * 16 + r) * LDSP + kg];
  #pragma unroll
  for (int n = 0; n < 4; ++n) bf[n] = *(const f16x8*)&Bsh[(wn + n * 16 + r) * LDSP + kg];
  #pragma unroll
  for (int m = 0; m < 4; ++m)
    #pragma unroll
    for (int n = 0; n < 4; ++n)
      acc[m][n] = __builtin_amdgcn_mfma_f32_16x16x32_f16(af[m], bf[n], acc[m][n], 0, 0, 0);
}

// ---------------- cores ----------------
template<int SCALE>
__device__ __forceinline__
void mm_at_core(f16* Ash, f16* Bsh, const float* Ab, long Ars,
                const float* Bb, long Brs, int K, const float* scale, int t, f32x4 acc[4][4])
{
  for (int k0 = 0; k0 < K; k0 += 32) {
    __syncthreads();
    stage_rows(Ash, Ab + k0, Ars, t);
    if (SCALE) stage_rows_scale(Bsh, Bb + k0, Brs, scale + k0, t);
    else       stage_rows(Bsh, Bb + k0, Brs, t);
    __syncthreads();
    mfma_step(Ash, Bsh, t, acc);
  }
}

__device__ __forceinline__
void mm_ab_core(f16* Ash, f16* Bsh, const float* Ab, long Ars,
                const float* Bb, long Brs, int K, int t, f32x4 acc[4][4])
{
  for (int k0 = 0; k0 < K; k0 += 32) {
    __syncthreads();
    stage_rows(Ash, Ab + k0, Ars, t);
    stage_vt(Bsh, Bb + (long)k0 * Brs, Brs, t);
    __syncthreads();
    mfma_step(Ash, Bsh, t, acc);
  }
}

__device__ __forceinline__
void store_tile(float* Cb, long Crs, int i0, int j0, int t, f32x4 acc[4][4])
{
  const int lane = t & 63, wid = t >> 6;
  const int wm = (wid >> 1) << 6, wn = (wid & 1) << 6;
  const int rq = (lane >> 4) << 2, cj = lane & 15;
  #pragma unroll
  for (int m = 0; m < 4; ++m)
    #pragma unroll
    for (int q = 0; q < 4; ++q) {
      const int row = i0 + wm + m * 16 + rq + q;
      #pragma unroll
      for (int n = 0; n < 4; ++n) {
        const int col = j0 + wn + n * 16 + cj;
        Cb[(long)row * Crs + col] = acc[m][n][q];
      }
    }
}

// ---------------- generic batched GEMM kernels ----------------
template<int SCALE, int RANK1>
__global__ __launch_bounds__(256)
void mm_at_kernel(const float* __restrict__ A, long Abs, long Ars,
                  const float* __restrict__ B, long Bbs, long Brs, int K,
                  const float* __restrict__ scale,
                  const float* __restrict__ ql, long qlbs,
                  const float* __restrict__ kl, long klbs,
                  float* __restrict__ C, long Cbs, long Crs)
{
  __shared__ __align__(16) f16 Ash[128 * LDSP];
  __shared__ __align__(16) f16 Bsh[128 * LDSP];
  const int z = blockIdx.z, t = threadIdx.x;
  const int i0 = blockIdx.y << 7, j0 = blockIdx.x << 7;
  f32x4 acc[4][4] = {};
  mm_at_core<SCALE>(Ash, Bsh, A + (long)z * Abs + (long)i0 * Ars, Ars,
                    B + (long)z * Bbs + (long)j0 * Brs, Brs, K, scale, t, acc);
  const int lane = t & 63, wid = t >> 6;
  const int wm = (wid >> 1) << 6, wn = (wid & 1) << 6;
  const int rq = (lane >> 4) << 2, cj = lane & 15;
  float* Cb = C + (long)z * Cbs;
  #pragma unroll
  for (int m = 0; m < 4; ++m)
    #pragma unroll
    for (int q = 0; q < 4; ++q) {
      const int row = i0 + wm + m * 16 + rq + q;
      const float qv = RANK1 ? ql[(long)z * qlbs + row] : 0.f;
      #pragma unroll
      for (int n = 0; n < 4; ++n) {
        const int col = j0 + wn + n * 16 + cj;
        float v = acc[m][n][q] + qv;
        if (RANK1) v += kl[(long)z * klbs + col];
        Cb[(long)row * Crs + col] = v;
      }
    }
}

__global__ __launch_bounds__(256)
void mm_ab_kernel(const float* __restrict__ A, long Abs, long Ars,
                  const float* __restrict__ B, long Bbs, long Brs, int K,
                  float* __restrict__ C, long Cbs, long Crs)
{
  __shared__ __align__(16) f16 Ash[128 * LDSP];
  __shared__ __align__(16) f16 Bsh[128 * LDSP];
  const int z = blockIdx.z, t = threadIdx.x;
  const int i0 = blockIdx.y << 7, j0 = blockIdx.x << 7;
  f32x4 acc[4][4] = {};
  mm_ab_core(Ash, Bsh, A + (long)z * Abs + (long)i0 * Ars, Ars,
             B + (long)z * Bbs + j0, Brs, K, t, acc);
  store_tile(C + (long)z * Cbs, Crs, i0, j0, t, acc);
}

// ---------------- stage A custom kernels (pair decode) ----------------
__device__ __forceinline__ void pair_decode(int pair, int& i, int& j) {
  i = pair / 3; const int r = pair - i * 3; j = r + (r >= i ? 1 : 0);
}

__global__ __launch_bounds__(256)
void stA_logits_kernel(const float* __restrict__ OPT, const float* __restrict__ w3,
                       const float* __restrict__ ql_all, const float* __restrict__ kl_all,
                       float* __restrict__ L)
{
  __shared__ __align__(16) f16 Ash[128 * LDSP];
  __shared__ __align__(16) f16 Bsh[128 * LDSP];
  const int z = blockIdx.z, t = threadIdx.x;
  const int pair = z >> 3, b8 = z & 7;
  int i, j; pair_decode(pair, i, j);
  const int bi = b8 * 4 + i, bj = b8 * 4 + j;
  const int i0 = blockIdx.y << 7, j0 = blockIdx.x << 7;
  f32x4 acc[4][4] = {};
  mm_at_core<1>(Ash, Bsh, OPT + (long)bi * LLBS + (long)i0 * HDIM, HDIM,
                OPT + (long)bj * LLBS + (long)j0 * HDIM, HDIM, HDIM, w3, t, acc);
  const float* qlp = ql_all + bi * 256;
  const float* klp = kl_all + bj * 256;
  float* Cb = L + (long)z * 65536;
  const int lane = t & 63, wid = t >> 6;
  const int wm = (wid >> 1) << 6, wn = (wid & 1) << 6;
  const int rq = (lane >> 4) << 2, cj = lane & 15;
  #pragma unroll
  for (int m = 0; m < 4; ++m)
    #pragma unroll
    for (int q = 0; q < 4; ++q) {
      const int row = i0 + wm + m * 16 + rq + q;
      const float qv = qlp[row];
      #pragma unroll
      for (int n = 0; n < 4; ++n) {
        const int col = j0 + wn + n * 16 + cj;
        Cb[(long)row * 256 + col] = acc[m][n][q] + qv + klp[col];
      }
    }
}

__global__ __launch_bounds__(256)
void stA_attn_kernel(const float* __restrict__ L, const float* __restrict__ OPT,
                     float* __restrict__ aBuf)
{
  __shared__ __align__(16) f16 Ash[128 * LDSP];
  __shared__ __align__(16) f16 Bsh[128 * LDSP];
  const int z = blockIdx.z, t = threadIdx.x;
  const int pair = z >> 3, b8 = z & 7;
  int i, j; pair_decode(pair, i, j);
  const int bj = b8 * 4 + j;
  const int i0 = blockIdx.y << 7, j0 = blockIdx.x << 7;
  f32x4 acc[4][4] = {};
  mm_ab_core(Ash, Bsh, L + (long)z * 65536 + (long)i0 * 256, 256,
             OPT + (long)bj * LLBS + j0, HDIM, 256, t, acc);
  store_tile(aBuf + (long)z * OPTBS, HDIM, i0, j0, t, acc);
}

// ---------------- stage A comp: fused 7-block concat-linear, all (b8,i) in one launch ----------------
__device__ __forceinline__ float4 f4mul(float4 a, float4 b){ return make_float4(a.x*b.x,a.y*b.y,a.z*b.z,a.w*b.w); }
__device__ __forceinline__ float4 f4sub(float4 a, float4 b){ return make_float4(a.x-b.x,a.y-b.y,a.z-b.z,a.w-b.w); }

__global__ __launch_bounds__(256)
void stA_comp_kernel(const float* __restrict__ OPT, const float* __restrict__ aBuf,
                     const float* __restrict__ W, const float* __restrict__ bias,
                     float* __restrict__ out)
{
  __shared__ __align__(16) f16 Ash[128 * LDSP];
  __shared__ __align__(16) f16 Wsh[128 * LDSP];
  const int z = blockIdx.z, t = threadIdx.x;     // z = b8*4 + i
  const int b8 = z >> 2, i = z & 3;
  const int i0 = blockIdx.y << 7, n0 = blockIdx.x << 7;
  const float* cur = OPT + (long)z * LLBS;
  const float* a0 = aBuf + (long)((i * 3 + 0) * 8 + b8) * OPTBS;
  const float* a1 = aBuf + (long)((i * 3 + 1) * 8 + b8) * OPTBS;
  const float* a2 = aBuf + (long)((i * 3 + 2) * 8 + b8) * OPTBS;
  const float* Wb = W + (long)n0 * 7168;
  f32x4 acc[4][4] = {};
  const int row = t >> 1, h = (t & 1) << 4;
  for (int k0 = 0; k0 < 7168; k0 += 32) {
    const int blk = k0 >> 10, kk = k0 & 1023;
    __syncthreads();
    {
      const long ro = (long)(i0 + row) * HDIM + kk + h;
      const float4* pc = (const float4*)(cur + ro);
      float4 a = pc[0], b = pc[1], c = pc[2], d = pc[3];
      if (blk) {
        const int m = (blk - 1) >> 1;
        const float* ap = (m == 0) ? a0 : (m == 1 ? a1 : a2);
        const float4* pa = (const float4*)(ap + ro);
        const float4 e = pa[0], f = pa[1], g = pa[2], hh = pa[3];
        if (blk & 1) { a = f4mul(a, e); b = f4mul(b, f); c = f4mul(c, g); d = f4mul(d, hh); }
        else         { a = f4sub(a, e); b = f4sub(b, f); c = f4sub(c, g); d = f4sub(d, hh); }
      }
      st16(&Ash[row * LDSP + h], a, b, c, d);
    }
    stage_rows(Wsh, Wb + k0, 7168, t);
    __syncthreads();
    mfma_step(Ash, Wsh, t, acc);
  }
  const int lane = t & 63, wid = t >> 6;
  const int wm = (wid >> 1) << 6, wn = (wid & 1) << 6;
  const int rq = (lane >> 4) << 2, cj = lane & 15;
  float* ob = out + (long)z * OPTBS;
  #pragma unroll
  for (int m = 0; m < 4; ++m)
    #pragma unroll
    for (int q = 0; q < 4; ++q) {
      const int r2 = i0 + wm + m * 16 + rq + q;
      #pragma unroll
      for (int n = 0; n < 4; ++n) {
        const int col = n0 + wn + n * 16 + cj;
        ob[(long)r2 * HDIM + col] = tanhf(acc[m][n][q] + bias[col]);
      }
    }
}

// ---------------- generic fused concat-linear (stages B, D, F) ----------------
struct FCSrc { const float* s0; const float* s1; long s0bs; long s1bs; int op; int pad; };
struct FCArgs {
  FCSrc src[4];
  int nblk; int act;            // 0=tanh, 1=relu, 2=sigmoid-lerp
  const float* W; const float* bias;
  float* out; long outbs;
  const float* e0; const float* e1; long e0bs; long e1bs;
};

__global__ __launch_bounds__(256)
void fc_mfma_kernel(FCArgs P)
{
  __shared__ __align__(16) f16 Ash[128 * LDSP];
  __shared__ __align__(16) f16 Wsh[128 * LDSP];
  const int b = blockIdx.z, t = threadIdx.x;
  const int i0 = blockIdx.y << 7, n0 = blockIdx.x << 7;
  const int Ktot = P.nblk << 10;
  const float* Wb = P.W + (long)n0 * Ktot;
  f32x4 acc[4][4] = {};
  const int row = t >> 1, h = (t & 1) << 4;
  for (int k0 = 0; k0 < Ktot; k0 += 32) {
    const FCSrc s = P.src[k0 >> 10];
    const int kk = k0 & 1023;
    __syncthreads();
    {
      const long ro = (long)(i0 + row) * HDIM + kk + h;
      const float4* p0 = (const float4*)(s.s0 + (long)b * s.s0bs + ro);
      float4 a = p0[0], bb = p0[1], c = p0[2], d = p0[3];
      if (s.op) {
        const float4* p1 = (const float4*)(s.s1 + (long)b * s.s1bs + ro);
        const float4 e = p1[0], f = p1[1], g = p1[2], hh = p1[3];
        if (s.op == 1) { a = f4mul(a, e); bb = f4mul(bb, f); c = f4mul(c, g); d = f4mul(d, hh); }
        else           { a = f4sub(a, e); bb = f4sub(bb, f); c = f4sub(c, g); d = f4sub(d, hh); }
      }
      st16(&Ash[row * LDSP + h], a, bb, c, d);
    }
    stage_rows(Wsh, Wb + k0, Ktot, t);
    __syncthreads();
    mfma_step(Ash, Wsh, t, acc);
  }
  const int lane = t & 63, wid = t >> 6;
  const int wm = (wid >> 1) << 6, wn = (wid & 1) << 6;
  const int rq = (lane >> 4) << 2, cj = lane & 15;
  #pragma unroll
  for (int m = 0; m < 4; ++m)
    #pragma unroll
    for (int q = 0; q < 4; ++q) {
      const int r2 = i0 + wm + m * 16 + rq + q;
      float* orow = P.out + (long)b * P.outbs + (long)r2 * HDIM;
      #pragma unroll
      for (int n = 0; n < 4; ++n) {
        const int col = n0 + wn + n * 16 + cj;
        float v = acc[m][n][q] + P.bias[col];
        if (P.act == 0) v = tanhf(v);
        else if (P.act == 1) v = fmaxf(v, 0.f);
        else {
          const float sg = 1.f / (1.f + __expf(-v));
          const float e = P.e0[(long)b * P.e0bs + (long)r2 * HDIM + col];
          const float c2 = P.e1[(long)b * P.e1bs + (long)r2 * HDIM + col];
          v = e * sg + c2 * (1.f - sg);
        }
        orow[col] = v;
      }
    }
}

// ---------------- rowdot / softmaxes / colmax (unchanged f32) ----------------
__global__ __launch_bounds__(256)
void rowdot_kernel(const float* __restrict__ base, long bs, int R,
                   const float* __restrict__ w, float* __restrict__ out)
{
  const int row  = blockIdx.x * 4 + (threadIdx.x >> 6);
  const int lane = threadIdx.x & 63;
  const int b = row / R, r = row - b * R;
  const float* p = base + (long)b * bs + (long)r * HDIM;
  float s = 0.f;
  #pragma unroll 4
  for (int d = lane; d < HDIM; d += 64) s += p[d] * w[d];
  #pragma unroll
  for (int off = 32; off; off >>= 1) s += __shfl_down(s, off, 64);
  if (lane == 0) out[row] = s;
}

template<int CNT>
__global__ __launch_bounds__(256)
void softmax_rows_kernel(float* __restrict__ L)
{
  const int row = blockIdx.x * 4 + (threadIdx.x >> 6);
  const int lane = threadIdx.x & 63;
  float* p = L + (long)row * (CNT * 64);
  float v[CNT];
  float m = -3.0e38f;
  #pragma unroll
  for (int u = 0; u < CNT; ++u) { v[u] = p[lane + (u << 6)]; m = fmaxf(m, v[u]); }
  #pragma unroll
  for (int off = 32; off; off >>= 1) m = fmaxf(m, __shfl_xor(m, off, 64));
  float s = 0.f;
  #pragma unroll
  for (int u = 0; u < CNT; ++u) { v[u] = __expf(v[u] - m); s += v[u]; }
  #pragma unroll
  for (int off = 32; off; off >>= 1) s += __shfl_xor(s, off, 64);
  const float inv = 1.f / s;
  #pragma unroll
  for (int u = 0; u < CNT; ++u) p[lane + (u << 6)] = v[u] * inv;
}

__global__ __launch_bounds__(256)
void softmax_cols_kernel(const float* __restrict__ L, float* __restrict__ out, int M, int N)
{
  const int b = blockIdx.y;
  const int j = blockIdx.x * 256 + threadIdx.x;
  const float* p = L + (long)b * M * N + j;
  float* o = out + (long)b * M * N + j;
  float m = -3.0e38f;
  for (int i = 0; i < M; ++i) m = fmaxf(m, p[(long)i * N]);
  float s = 0.f;
  for (int i = 0; i < M; ++i) { const float e = __expf(p[(long)i * N] - m); o[(long)i * N] = e; s += e; }
  const float inv = 1.f / s;
  for (int i = 0; i < M; ++i) o[(long)i * N] *= inv;
}

__global__ __launch_bounds__(256)
void colmax_kernel(const float* __restrict__ X, float* __restrict__ out)
{
  const int b = blockIdx.y;
  const int d = blockIdx.x * 256 + threadIdx.x;
  const float* p = X + (long)b * (256 * HDIM) + d;
  float m = -3.0e38f;
  for (int r = 0; r < 256; ++r) m = fmaxf(m, p[r * HDIM]);
  out[b * HDIM + d] = m;
}

extern "C" void kernel_launch(void* const* d_in, const int* in_sizes, int n_in,
                              void* d_out, int out_size, void* d_ws, size_t ws_size,
                              hipStream_t stream)
{
  (void)in_sizes; (void)n_in; (void)out_size; (void)ws_size;
  const float* last   = (const float*)d_in[4];
  const float* ow1    = (const float*)d_in[5];
  const float* ow2    = (const float*)d_in[6];
  const float* ow3    = (const float*)d_in[7];
  const float* dw1    = (const float*)d_in[8];
  const float* dw2    = (const float*)d_in[9];
  const float* dw3    = (const float*)d_in[10];
  const float* sw1    = (const float*)d_in[11];
  const float* sw2    = (const float*)d_in[12];
  const float* sw3    = (const float*)d_in[13];
  const float* comp_w = (const float*)d_in[14];
  const float* comp_b = (const float*)d_in[15];
  const float* gate_w = (const float*)d_in[16];
  const float* gate_b = (const float*)d_in[17];
  const float* attn_w = (const float*)d_in[18];
  const float* attn_b = (const float*)d_in[19];
  const float* self_w = (const float*)d_in[20];
  const float* self_b = (const float*)d_in[21];

  const float* OPT = last + 768 * 1024;   // opt_enc view: (32, 256, H), batch stride LLBS

  float* ws = (float*)d_ws;
  long off = 0;
  auto alloc = [&](long n) { float* p = ws + off; off += n; return p; };
  float* ql_all = alloc(8192);
  float* kl_all = alloc(8192);
  float* ql_c   = alloc(8192);
  float* kl_c   = alloc(24576);
  float* ql_e   = alloc(8192);
  float* kl_e   = alloc(8192);
  float* aBuf   = alloc(12L * 8 * 256 * 1024);
  float* L      = alloc(32L * 256 * 768);
  float* kq     = alloc(32L * 256 * 768);
  float* co_w   = alloc(32L * 256 * 256);
  float* buf1   = alloc(32L * 256 * 1024);       // opt_corr, then attn_a
  float* buf2   = alloc(32L * 256 * 1024);       // option, then sa
  float* buf3   = alloc(32L * 256 * 1024);       // co, then fusion2
  float* buf4   = alloc(32L * 256 * 1024);       // fusion

  // ---- stage A ----
  rowdot_kernel<<<8192 / 4, 256, 0, stream>>>(OPT, LLBS, 256, ow1, ql_all);
  rowdot_kernel<<<8192 / 4, 256, 0, stream>>>(OPT, LLBS, 256, ow2, kl_all);
  stA_logits_kernel<<<dim3(2, 2, 96), 256, 0, stream>>>(OPT, ow3, ql_all, kl_all, L);
  softmax_rows_kernel<4><<<(96 * 256) / 4, 256, 0, stream>>>(L);
  stA_attn_kernel<<<dim3(8, 2, 96), 256, 0, stream>>>(L, OPT, aBuf);
  stA_comp_kernel<<<dim3(8, 2, 32), 256, 0, stream>>>(OPT, aBuf, comp_w, comp_b, buf1);

  // ---- stage B: gate ----
  {
    FCArgs P = {};
    P.src[0] = {OPT,  nullptr, LLBS,  0, 0, 0};
    P.src[1] = {buf1, nullptr, OPTBS, 0, 0, 0};
    P.nblk = 2; P.act = 2; P.W = gate_w; P.bias = gate_b;
    P.e0 = OPT; P.e0bs = LLBS; P.e1 = buf1; P.e1bs = OPTBS;
    P.out = buf2; P.outbs = OPTBS;
    fc_mfma_kernel<<<dim3(8, 2, 32), 256, 0, stream>>>(P);
  }

  // ---- stage C: doc attention ----
  rowdot_kernel<<<8192 / 4, 256, 0, stream>>>(buf2, OPTBS, 256, dw1, ql_c);
  rowdot_kernel<<<24576 / 4, 256, 0, stream>>>(last, LLBS, 768, dw2, kl_c);
  mm_at_kernel<1, 1><<<dim3(6, 2, 32), 256, 0, stream>>>(buf2, OPTBS, HDIM, last, LLBS, HDIM, HDIM,
                                                         dw3, ql_c, 256, kl_c, 768, L, 196608, 768);
  softmax_cols_kernel<<<dim3(3, 32), 256, 0, stream>>>(L, kq, 256, 768);
  softmax_rows_kernel<12><<<8192 / 4, 256, 0, stream>>>(L);
  mm_ab_kernel<<<dim3(8, 2, 32), 256, 0, stream>>>(L, 196608, 768, last, LLBS, HDIM, 768,
                                                   buf1, OPTBS, HDIM);
  mm_at_kernel<0, 0><<<dim3(2, 2, 32), 256, 0, stream>>>(L, 196608, 768, kq, 196608, 768, 768,
                                                         nullptr, nullptr, 0, nullptr, 0, co_w, 65536, 256);
  mm_ab_kernel<<<dim3(8, 2, 32), 256, 0, stream>>>(co_w, 65536, 256, buf2, OPTBS, HDIM, 256,
                                                   buf3, OPTBS, HDIM);

  // ---- stage D: fusion ----
  {
    FCArgs P = {};
    P.src[0] = {buf2, nullptr, OPTBS, 0, 0, 0};
    P.src[1] = {buf1, nullptr, OPTBS, 0, 0, 0};
    P.src[2] = {buf3, nullptr, OPTBS, 0, 0, 0};
    P.nblk = 3; P.act = 1; P.W = attn_w; P.bias = attn_b;
    P.out = buf4; P.outbs = OPTBS;
    fc_mfma_kernel<<<dim3(8, 2, 32), 256, 0, stream>>>(P);
  }

  // ---- stage E: self-attention ----
  rowdot_kernel<<<8192 / 4, 256, 0, stream>>>(buf4, OPTBS, 256, sw1, ql_e);
  rowdot_kernel<<<8192 / 4, 256, 0, stream>>>(buf4, OPTBS, 256, sw2, kl_e);
  mm_at_kernel<1, 1><<<dim3(2, 2, 32), 256, 0, stream>>>(buf4, OPTBS, HDIM, buf4, OPTBS, HDIM, HDIM,
                                                         sw3, ql_e, 256, kl_e, 256, L, 65536, 256);
  softmax_rows_kernel<4><<<8192 / 4, 256, 0, stream>>>(L);
  mm_ab_kernel<<<dim3(8, 2, 32), 256, 0, stream>>>(L, 65536, 256, buf4, OPTBS, HDIM, 256,
                                                   buf2, OPTBS, HDIM);

  // ---- stage F: fusion2 ----
  {
    FCArgs P = {};
    P.src[0] = {buf4, nullptr, OPTBS, 0, 0, 0};
    P.src[1] = {buf2, nullptr, OPTBS, 0, 0, 0};
    P.src[2] = {buf4, buf2, OPTBS, OPTBS, 1, 0};
    P.src[3] = {buf4, buf2, OPTBS, OPTBS, 2, 0};
    P.nblk = 4; P.act = 1; P.W = self_w; P.bias = self_b;
    P.out = buf3; P.outbs = OPTBS;
    fc_mfma_kernel<<<dim3(8, 2, 32), 256, 0, stream>>>(P);
  }

  // ---- stage G ----
  colmax_kernel<<<dim3(4, 32), 256, 0, stream>>>(buf3, (float*)d_out);
}

// Round 4
// 1348.377 us; speedup vs baseline: 4.3194x; 1.4701x over previous
//
#include <hip/hip_runtime.h>

#define HDIM 1024
#define LLBS 1048576L   // 1024*1024 elements
#define OPTBS 262144L   // 256*1024 elements
#define LDSP 72         // padded LDS row length in f16 (144 B): 2-way (free) frag reads

typedef _Float16 f16;
typedef __attribute__((ext_vector_type(8))) _Float16 f16x8;
typedef __attribute__((ext_vector_type(4))) _Float16 f16x4;
typedef __attribute__((ext_vector_type(4))) float    f32x4;

// ---------------- f32 -> f16 conversion (grid-stride, 8 elems/thread) ----------------
__global__ __launch_bounds__(256)
void cvt_kernel(const float* __restrict__ src, f16* __restrict__ dst, long n)
{
  long i = ((long)blockIdx.x * 256 + threadIdx.x) * 8;
  const long stride = (long)gridDim.x * 256 * 8;
  for (; i < n; i += stride) {
    const float4 a = *(const float4*)(src + i);
    const float4 b = *(const float4*)(src + i + 4);
    *(f16x8*)(dst + i) = f16x8{(f16)a.x,(f16)a.y,(f16)a.z,(f16)a.w,
                               (f16)b.x,(f16)b.y,(f16)b.z,(f16)b.w};
  }
}

// ---------------- staging: 128 rows x 64 k, f16 -> padded LDS ----------------
__device__ __forceinline__
void stage_rows(f16* __restrict__ sh, const f16* __restrict__ src, long rs, int t)
{
  const int row = t >> 1, h = (t & 1) << 5;
  const f16x8* p = (const f16x8*)(src + (long)row * rs + h);
  const f16x8 a = p[0], b = p[1], c = p[2], d = p[3];
  f16x8* q = (f16x8*)&sh[row * LDSP + h];
  q[0] = a; q[1] = b; q[2] = c; q[3] = d;
}

__device__ __forceinline__ f16x8 sc8(f16x8 v, const float* s)
{
  const float4 s0 = *(const float4*)s, s1 = *(const float4*)(s + 4);
  f16x8 r;
  r[0]=(f16)((float)v[0]*s0.x); r[1]=(f16)((float)v[1]*s0.y);
  r[2]=(f16)((float)v[2]*s0.z); r[3]=(f16)((float)v[3]*s0.w);
  r[4]=(f16)((float)v[4]*s1.x); r[5]=(f16)((float)v[5]*s1.y);
  r[6]=(f16)((float)v[6]*s1.z); r[7]=(f16)((float)v[7]*s1.w);
  return r;
}

__device__ __forceinline__
void stage_rows_scale(f16* __restrict__ sh, const f16* __restrict__ src, long rs,
                      const float* __restrict__ sc, int t)
{
  const int row = t >> 1, h = (t & 1) << 5;
  const f16x8* p = (const f16x8*)(src + (long)row * rs + h);
  f16x8* q = (f16x8*)&sh[row * LDSP + h];
  #pragma unroll
  for (int e = 0; e < 4; ++e) q[e] = sc8(p[e], sc + h + e * 8);
}

// V-tile transpose staging: src rows are k (stride rs), cols j; store Vt[j][k]
__device__ __forceinline__
void stage_vt(f16* __restrict__ sh, const f16* __restrict__ src, long rs, int t)
{
  const int jc = (t & 31) << 2, kg = (t >> 5) << 3;
  const f16* p = src + (long)kg * rs + jc;
  f16x4 r[8];
  #pragma unroll
  for (int e = 0; e < 8; ++e) r[e] = *(const f16x4*)(p + (long)e * rs);
  #pragma unroll
  for (int c = 0; c < 4; ++c) {
    *(f16x8*)&sh[(jc + c) * LDSP + kg] =
      f16x8{r[0][c], r[1][c], r[2][c], r[3][c], r[4][c], r[5][c], r[6][c], r[7][c]};
  }
}

// ---------------- MFMA consume: 4 waves 2x2, each 64x64 via 4x4 of 16x16x32, K=64 ----------------
__device__ __forceinline__
void mfma_step(const f16* __restrict__ Ash, const f16* __restrict__ Bsh, int t, f32x4 acc[4][4])
{
  const int lane = t & 63, wid = t >> 6;
  const int wm = (wid >> 1) << 6, wn = (wid & 1) << 6;
  const int r = lane & 15;
  #pragma unroll
  for (int kh = 0; kh < 2; ++kh) {
    const int kg = (kh << 5) + ((lane >> 4) << 3);
    f16x8 af[4], bf[4];
    #pragma unroll
    for (int m = 0; m < 4; ++m) af[m] = *(const f16x8*)&Ash[(wm + m * 16 + r) * LDSP + kg];
    #pragma unroll
    for (int n = 0; n < 4; ++n) bf[n] = *(const f16x8*)&Bsh[(wn + n * 16 + r) * LDSP + kg];
    #pragma unroll
    for (int m = 0; m < 4; ++m)
      #pragma unroll
      for (int n = 0; n < 4; ++n)
        acc[m][n] = __builtin_amdgcn_mfma_f32_16x16x32_f16(af[m], bf[n], acc[m][n], 0, 0, 0);
  }
}

// ---------------- cores ----------------
template<int SCALE>
__device__ __forceinline__
void mm_at_core(f16* Ash, f16* Bsh, const f16* Ab, long Ars,
                const f16* Bb, long Brs, int K, const float* scale, int t, f32x4 acc[4][4])
{
  for (int k0 = 0; k0 < K; k0 += 64) {
    __syncthreads();
    stage_rows(Ash, Ab + k0, Ars, t);
    if (SCALE) stage_rows_scale(Bsh, Bb + k0, Brs, scale + k0, t);
    else       stage_rows(Bsh, Bb + k0, Brs, t);
    __syncthreads();
    mfma_step(Ash, Bsh, t, acc);
  }
}

__device__ __forceinline__
void mm_ab_core(f16* Ash, f16* Bsh, const f16* Ab, long Ars,
                const f16* Bb, long Brs, int K, int t, f32x4 acc[4][4])
{
  for (int k0 = 0; k0 < K; k0 += 64) {
    __syncthreads();
    stage_rows(Ash, Ab + k0, Ars, t);
    stage_vt(Bsh, Bb + (long)k0 * Brs, Brs, t);
    __syncthreads();
    mfma_step(Ash, Bsh, t, acc);
  }
}

// ---------------- generic batched GEMM kernels ----------------
// HOUT=1: f16 C; HOUT=0: f32 C (+ optional rank1)
template<int SCALE, int RANK1, int HOUT>
__global__ __launch_bounds__(256)
void mm_at_kernel(const f16* __restrict__ A, long Abs, long Ars,
                  const f16* __restrict__ B, long Bbs, long Brs, int K,
                  const float* __restrict__ scale,
                  const float* __restrict__ ql, long qlbs,
                  const float* __restrict__ kl, long klbs,
                  void* __restrict__ C, long Cbs, long Crs)
{
  __shared__ __align__(16) f16 Ash[128 * LDSP];
  __shared__ __align__(16) f16 Bsh[128 * LDSP];
  const int z = blockIdx.z, t = threadIdx.x;
  const int i0 = blockIdx.y << 7, j0 = blockIdx.x << 7;
  f32x4 acc[4][4] = {};
  mm_at_core<SCALE>(Ash, Bsh, A + (long)z * Abs + (long)i0 * Ars, Ars,
                    B + (long)z * Bbs + (long)j0 * Brs, Brs, K, scale, t, acc);
  const int lane = t & 63, wid = t >> 6;
  const int wm = (wid >> 1) << 6, wn = (wid & 1) << 6;
  const int rq = (lane >> 4) << 2, cj = lane & 15;
  #pragma unroll
  for (int m = 0; m < 4; ++m)
    #pragma unroll
    for (int q = 0; q < 4; ++q) {
      const int row = i0 + wm + m * 16 + rq + q;
      const float qv = RANK1 ? ql[(long)z * qlbs + row] : 0.f;
      #pragma unroll
      for (int n = 0; n < 4; ++n) {
        const int col = j0 + wn + n * 16 + cj;
        float v = acc[m][n][q] + qv;
        if (RANK1) v += kl[(long)z * klbs + col];
        if (HOUT) ((f16*)C)[(long)z * Cbs + (long)row * Crs + col] = (f16)v;
        else      ((float*)C)[(long)z * Cbs + (long)row * Crs + col] = v;
      }
    }
}

__global__ __launch_bounds__(256)
void mm_ab_kernel(const f16* __restrict__ A, long Abs, long Ars,
                  const f16* __restrict__ B, long Bbs, long Brs, int K,
                  f16* __restrict__ C, long Cbs, long Crs)
{
  __shared__ __align__(16) f16 Ash[128 * LDSP];
  __shared__ __align__(16) f16 Bsh[128 * LDSP];
  const int z = blockIdx.z, t = threadIdx.x;
  const int i0 = blockIdx.y << 7, j0 = blockIdx.x << 7;
  f32x4 acc[4][4] = {};
  mm_ab_core(Ash, Bsh, A + (long)z * Abs + (long)i0 * Ars, Ars,
             B + (long)z * Bbs + j0, Brs, K, t, acc);
  const int lane = t & 63, wid = t >> 6;
  const int wm = (wid >> 1) << 6, wn = (wid & 1) << 6;
  const int rq = (lane >> 4) << 2, cj = lane & 15;
  f16* Cb = C + (long)z * Cbs;
  #pragma unroll
  for (int m = 0; m < 4; ++m)
    #pragma unroll
    for (int q = 0; q < 4; ++q) {
      const int row = i0 + wm + m * 16 + rq + q;
      #pragma unroll
      for (int n = 0; n < 4; ++n) {
        const int col = j0 + wn + n * 16 + cj;
        Cb[(long)row * Crs + col] = (f16)acc[m][n][q];
      }
    }
}

// ---------------- stage A custom kernels ----------------
__device__ __forceinline__ void pair_decode(int pair, int& i, int& j) {
  i = pair / 3; const int r = pair - i * 3; j = r + (r >= i ? 1 : 0);
}

__global__ __launch_bounds__(256)
void stA_logits_kernel(const f16* __restrict__ OPT, const float* __restrict__ w3,
                       const float* __restrict__ ql_all, const float* __restrict__ kl_all,
                       float* __restrict__ L)
{
  __shared__ __align__(16) f16 Ash[128 * LDSP];
  __shared__ __align__(16) f16 Bsh[128 * LDSP];
  const int z = blockIdx.z, t = threadIdx.x;
  const int pair = z >> 3, b8 = z & 7;
  int i, j; pair_decode(pair, i, j);
  const int bi = b8 * 4 + i, bj = b8 * 4 + j;
  const int i0 = blockIdx.y << 7, j0 = blockIdx.x << 7;
  f32x4 acc[4][4] = {};
  mm_at_core<1>(Ash, Bsh, OPT + (long)bi * LLBS + (long)i0 * HDIM, HDIM,
                OPT + (long)bj * LLBS + (long)j0 * HDIM, HDIM, HDIM, w3, t, acc);
  const float* qlp = ql_all + bi * 256;
  const float* klp = kl_all + bj * 256;
  float* Cb = L + (long)z * 65536;
  const int lane = t & 63, wid = t >> 6;
  const int wm = (wid >> 1) << 6, wn = (wid & 1) << 6;
  const int rq = (lane >> 4) << 2, cj = lane & 15;
  #pragma unroll
  for (int m = 0; m < 4; ++m)
    #pragma unroll
    for (int q = 0; q < 4; ++q) {
      const int row = i0 + wm + m * 16 + rq + q;
      const float qv = qlp[row];
      #pragma unroll
      for (int n = 0; n < 4; ++n) {
        const int col = j0 + wn + n * 16 + cj;
        Cb[(long)row * 256 + col] = acc[m][n][q] + qv + klp[col];
      }
    }
}

__global__ __launch_bounds__(256)
void stA_attn_kernel(const f16* __restrict__ P, const f16* __restrict__ OPT,
                     f16* __restrict__ aBuf)
{
  __shared__ __align__(16) f16 Ash[128 * LDSP];
  __shared__ __align__(16) f16 Bsh[128 * LDSP];
  const int z = blockIdx.z, t = threadIdx.x;
  const int pair = z >> 3, b8 = z & 7;
  int i, j; pair_decode(pair, i, j);
  const int bj = b8 * 4 + j;
  const int i0 = blockIdx.y << 7, j0 = blockIdx.x << 7;
  f32x4 acc[4][4] = {};
  mm_ab_core(Ash, Bsh, P + (long)z * 65536 + (long)i0 * 256, 256,
             OPT + (long)bj * LLBS + j0, HDIM, 256, t, acc);
  const int lane = t & 63, wid = t >> 6;
  const int wm = (wid >> 1) << 6, wn = (wid & 1) << 6;
  const int rq = (lane >> 4) << 2, cj = lane & 15;
  f16* Cb = aBuf + (long)z * OPTBS;
  #pragma unroll
  for (int m = 0; m < 4; ++m)
    #pragma unroll
    for (int q = 0; q < 4; ++q) {
      const int row = i0 + wm + m * 16 + rq + q;
      #pragma unroll
      for (int n = 0; n < 4; ++n)
        Cb[(long)row * HDIM + j0 + wn + n * 16 + cj] = (f16)acc[m][n][q];
    }
}

// ---------------- stage A comp: fused 7-block concat-linear, XCD-swizzled flat grid ----------------
__global__ __launch_bounds__(256)
void stA_comp_kernel(const f16* __restrict__ OPT, const f16* __restrict__ aBuf,
                     const f16* __restrict__ W, const float* __restrict__ bias,
                     f16* __restrict__ out)
{
  __shared__ __align__(16) f16 Ash[128 * LDSP];
  __shared__ __align__(16) f16 Wsh[128 * LDSP];
  const int Lb = blockIdx.x, t = threadIdx.x;
  // XCD swizzle: 8 n0-blocks of one (i0,z) group share an XCD (assuming XCD = id%8)
  const int c = Lb & 7, w = Lb >> 3;
  const int n0 = (w >> 3) << 7;
  const int g = (c << 3) | (w & 7);       // 0..63
  const int i0 = (g & 1) << 7;
  const int z = g >> 1;                   // 0..31 = b8*4 + i
  const int b8 = z >> 2, i = z & 3;
  const f16* cur = OPT + (long)z * LLBS;
  const f16* a0 = aBuf + (long)((i * 3 + 0) * 8 + b8) * OPTBS;
  const f16* a1 = aBuf + (long)((i * 3 + 1) * 8 + b8) * OPTBS;
  const f16* a2 = aBuf + (long)((i * 3 + 2) * 8 + b8) * OPTBS;
  const f16* Wb = W + (long)n0 * 7168;
  f32x4 acc[4][4] = {};
  const int row = t >> 1, h = (t & 1) << 5;
  for (int k0 = 0; k0 < 7168; k0 += 64) {
    const int blk = k0 >> 10, kk = k0 & 1023;
    __syncthreads();
    {
      const long ro = (long)(i0 + row) * HDIM + kk + h;
      const f16x8* pc = (const f16x8*)(cur + ro);
      f16x8 a = pc[0], b = pc[1], cc = pc[2], d = pc[3];
      if (blk) {
        const int m = (blk - 1) >> 1;
        const f16* ap = (m == 0) ? a0 : (m == 1 ? a1 : a2);
        const f16x8* pa = (const f16x8*)(ap + ro);
        const f16x8 e = pa[0], f = pa[1], gg = pa[2], hh = pa[3];
        if (blk & 1) { a *= e; b *= f; cc *= gg; d *= hh; }
        else         { a -= e; b -= f; cc -= gg; d -= hh; }
      }
      f16x8* q = (f16x8*)&Ash[row * LDSP + h];
      q[0] = a; q[1] = b; q[2] = cc; q[3] = d;
    }
    stage_rows(Wsh, Wb + k0, 7168, t);
    __syncthreads();
    mfma_step(Ash, Wsh, t, acc);
  }
  const int lane = t & 63, wid = t >> 6;
  const int wm = (wid >> 1) << 6, wn = (wid & 1) << 6;
  const int rq = (lane >> 4) << 2, cj = lane & 15;
  f16* ob = out + (long)z * OPTBS;
  #pragma unroll
  for (int m = 0; m < 4; ++m)
    #pragma unroll
    for (int q = 0; q < 4; ++q) {
      const int r2 = i0 + wm + m * 16 + rq + q;
      #pragma unroll
      for (int n = 0; n < 4; ++n) {
        const int col = n0 + wn + n * 16 + cj;
        ob[(long)r2 * HDIM + col] = (f16)tanhf(acc[m][n][q] + bias[col]);
      }
    }
}

// ---------------- generic fused concat-linear (stages B, D, F), XCD-swizzled ----------------
struct FCSrc { const f16* s0; const f16* s1; long s0bs; long s1bs; int op; int pad; };
struct FCArgs {
  FCSrc src[4];
  int nblk; int act;            // 0=tanh, 1=relu, 2=sigmoid-lerp
  const f16* W; const float* bias;
  f16* out; long outbs;
  const f16* e0; const f16* e1; long e0bs; long e1bs;
};

__global__ __launch_bounds__(256)
void fc_mfma_kernel(FCArgs P)
{
  __shared__ __align__(16) f16 Ash[128 * LDSP];
  __shared__ __align__(16) f16 Wsh[128 * LDSP];
  const int Lb = blockIdx.x, t = threadIdx.x;
  const int c = Lb & 7, w = Lb >> 3;
  const int n0 = (w >> 3) << 7;
  const int g = (c << 3) | (w & 7);
  const int i0 = (g & 1) << 7;
  const int b = g >> 1;
  const int Ktot = P.nblk << 10;
  const f16* Wb = P.W + (long)n0 * Ktot;
  f32x4 acc[4][4] = {};
  const int row = t >> 1, h = (t & 1) << 5;
  for (int k0 = 0; k0 < Ktot; k0 += 64) {
    const FCSrc s = P.src[k0 >> 10];
    const int kk = k0 & 1023;
    __syncthreads();
    {
      const long ro = (long)(i0 + row) * HDIM + kk + h;
      const f16x8* p0 = (const f16x8*)(s.s0 + (long)b * s.s0bs + ro);
      f16x8 a = p0[0], bb = p0[1], cc = p0[2], d = p0[3];
      if (s.op) {
        const f16x8* p1 = (const f16x8*)(s.s1 + (long)b * s.s1bs + ro);
        const f16x8 e = p1[0], f = p1[1], gg = p1[2], hh = p1[3];
        if (s.op == 1) { a *= e; bb *= f; cc *= gg; d *= hh; }
        else           { a -= e; bb -= f; cc -= gg; d -= hh; }
      }
      f16x8* q = (f16x8*)&Ash[row * LDSP + h];
      q[0] = a; q[1] = bb; q[2] = cc; q[3] = d;
    }
    stage_rows(Wsh, Wb + k0, Ktot, t);
    __syncthreads();
    mfma_step(Ash, Wsh, t, acc);
  }
  const int lane = t & 63, wid = t >> 6;
  const int wm = (wid >> 1) << 6, wn = (wid & 1) << 6;
  const int rq = (lane >> 4) << 2, cj = lane & 15;
  #pragma unroll
  for (int m = 0; m < 4; ++m)
    #pragma unroll
    for (int q = 0; q < 4; ++q) {
      const int r2 = i0 + wm + m * 16 + rq + q;
      f16* orow = P.out + (long)b * P.outbs + (long)r2 * HDIM;
      #pragma unroll
      for (int n = 0; n < 4; ++n) {
        const int col = n0 + wn + n * 16 + cj;
        float v = acc[m][n][q] + P.bias[col];
        if (P.act == 0) v = tanhf(v);
        else if (P.act == 1) v = fmaxf(v, 0.f);
        else {
          const float sg = 1.f / (1.f + __expf(-v));
          const float e = (float)P.e0[(long)b * P.e0bs + (long)r2 * HDIM + col];
          const float c2 = (float)P.e1[(long)b * P.e1bs + (long)r2 * HDIM + col];
          v = e * sg + c2 * (1.f - sg);
        }
        orow[col] = (f16)v;
      }
    }
}

// ---------------- rowdot / softmaxes / colmax ----------------
__global__ __launch_bounds__(256)
void rowdot_kernel(const f16* __restrict__ base, long bs, int R,
                   const float* __restrict__ w, float* __restrict__ out)
{
  const int row  = blockIdx.x * 4 + (threadIdx.x >> 6);
  const int lane = threadIdx.x & 63;
  const int b = row / R, r = row - b * R;
  const f16* p = base + (long)b * bs + (long)r * HDIM;
  float s = 0.f;
  #pragma unroll 4
  for (int d = lane; d < HDIM; d += 64) s += (float)p[d] * w[d];
  #pragma unroll
  for (int off = 32; off; off >>= 1) s += __shfl_down(s, off, 64);
  if (lane == 0) out[row] = s;
}

template<int CNT>
__global__ __launch_bounds__(256)
void softmax_rows_kernel(const float* __restrict__ L, f16* __restrict__ P)
{
  const int row = blockIdx.x * 4 + (threadIdx.x >> 6);
  const int lane = threadIdx.x & 63;
  const float* p = L + (long)row * (CNT * 64);
  f16* o = P + (long)row * (CNT * 64);
  float v[CNT];
  float m = -3.0e38f;
  #pragma unroll
  for (int u = 0; u < CNT; ++u) { v[u] = p[lane + (u << 6)]; m = fmaxf(m, v[u]); }
  #pragma unroll
  for (int off = 32; off; off >>= 1) m = fmaxf(m, __shfl_xor(m, off, 64));
  float s = 0.f;
  #pragma unroll
  for (int u = 0; u < CNT; ++u) { v[u] = __expf(v[u] - m); s += v[u]; }
  #pragma unroll
  for (int off = 32; off; off >>= 1) s += __shfl_xor(s, off, 64);
  const float inv = 1.f / s;
  #pragma unroll
  for (int u = 0; u < CNT; ++u) o[lane + (u << 6)] = (f16)(v[u] * inv);
}

__global__ __launch_bounds__(256)
void softmax_cols_kernel(const float* __restrict__ L, f16* __restrict__ out, int M, int N)
{
  const int b = blockIdx.y;
  const int j = blockIdx.x * 256 + threadIdx.x;
  const float* p = L + (long)b * M * N + j;
  f16* o = out + (long)b * M * N + j;
  float m = -3.0e38f;
  for (int i = 0; i < M; ++i) m = fmaxf(m, p[(long)i * N]);
  float s = 0.f;
  for (int i = 0; i < M; ++i) { const float e = __expf(p[(long)i * N] - m); o[(long)i * N] = (f16)e; s += e; }
  const float inv = 1.f / s;
  for (int i = 0; i < M; ++i) o[(long)i * N] = (f16)((float)o[(long)i * N] * inv);
}

__global__ __launch_bounds__(256)
void colmax_kernel(const f16* __restrict__ X, float* __restrict__ out)
{
  const int b = blockIdx.y;
  const int d = blockIdx.x * 256 + threadIdx.x;
  const f16* p = X + (long)b * (256 * HDIM) + d;
  float m = -3.0e38f;
  for (int r = 0; r < 256; ++r) m = fmaxf(m, (float)p[r * HDIM]);
  out[b * HDIM + d] = m;
}

extern "C" void kernel_launch(void* const* d_in, const int* in_sizes, int n_in,
                              void* d_out, int out_size, void* d_ws, size_t ws_size,
                              hipStream_t stream)
{
  (void)in_sizes; (void)n_in; (void)out_size; (void)ws_size;
  const float* last   = (const float*)d_in[4];
  const float* ow1    = (const float*)d_in[5];
  const float* ow2    = (const float*)d_in[6];
  const float* ow3    = (const float*)d_in[7];
  const float* dw1    = (const float*)d_in[8];
  const float* dw2    = (const float*)d_in[9];
  const float* dw3    = (const float*)d_in[10];
  const float* sw1    = (const float*)d_in[11];
  const float* sw2    = (const float*)d_in[12];
  const float* sw3    = (const float*)d_in[13];
  const float* comp_w = (const float*)d_in[14];
  const float* comp_b = (const float*)d_in[15];
  const float* gate_w = (const float*)d_in[16];
  const float* gate_b = (const float*)d_in[17];
  const float* attn_w = (const float*)d_in[18];
  const float* attn_b = (const float*)d_in[19];
  const float* self_w = (const float*)d_in[20];
  const float* self_b = (const float*)d_in[21];

  char* base = (char*)d_ws;
  size_t off = 0;
  auto af = [&](long n) { float* p = (float*)(base + off); off = (off + n * 4 + 15) & ~15UL; return p; };
  auto ah = [&](long n) { f16* p = (f16*)(base + off); off = (off + n * 2 + 15) & ~15UL; return p; };

  f16* lastH = ah(33554432L);            // f16 copy of last_layer
  f16* compH = ah(7340032L);
  f16* gateH = ah(2097152L);
  f16* attnH = ah(3145728L);
  f16* selfH = ah(4194304L);
  f16* aBuf  = ah(96L * OPTBS);          // cross-option attention outputs
  f16* pA    = ah(96L * 65536);          // stage A probs
  f16* awC   = ah(32L * 196608);         // stage C row-softmax probs
  f16* kqC   = ah(32L * 196608);         // stage C col-softmax probs
  f16* pE    = ah(32L * 65536);          // stage E probs
  f16* co_wH = ah(32L * 65536);
  f16* buf1  = ah(32L * OPTBS);          // opt_corr, then attn_a
  f16* buf2  = ah(32L * OPTBS);          // option, then sa
  f16* buf3  = ah(32L * OPTBS);          // co, then fusion2
  f16* buf4  = ah(32L * OPTBS);          // fusion
  float* L   = af(32L * 196608);         // f32 logits scratch (A/C/E reuse)
  float* ql_all = af(8192); float* kl_all = af(8192);
  float* ql_c   = af(8192); float* kl_c   = af(24576);
  float* ql_e   = af(8192); float* kl_e   = af(8192);

  const f16* OPTH = lastH + 768 * 1024;  // opt view (32,256,H), batch stride LLBS

  // ---- conversions ----
  cvt_kernel<<<2048, 256, 0, stream>>>(last,   lastH, 33554432L);
  cvt_kernel<<<512,  256, 0, stream>>>(comp_w, compH, 7340032L);
  cvt_kernel<<<256,  256, 0, stream>>>(gate_w, gateH, 2097152L);
  cvt_kernel<<<256,  256, 0, stream>>>(attn_w, attnH, 3145728L);
  cvt_kernel<<<256,  256, 0, stream>>>(self_w, selfH, 4194304L);

  // ---- stage A ----
  rowdot_kernel<<<2048, 256, 0, stream>>>(OPTH, LLBS, 256, ow1, ql_all);
  rowdot_kernel<<<2048, 256, 0, stream>>>(OPTH, LLBS, 256, ow2, kl_all);
  stA_logits_kernel<<<dim3(2, 2, 96), 256, 0, stream>>>(OPTH, ow3, ql_all, kl_all, L);
  softmax_rows_kernel<4><<<(96 * 256) / 4, 256, 0, stream>>>(L, pA);
  stA_attn_kernel<<<dim3(8, 2, 96), 256, 0, stream>>>(pA, OPTH, aBuf);
  stA_comp_kernel<<<512, 256, 0, stream>>>(OPTH, aBuf, compH, comp_b, buf1);

  // ---- stage B: gate ----
  {
    FCArgs P = {};
    P.src[0] = {OPTH, nullptr, LLBS,  0, 0, 0};
    P.src[1] = {buf1, nullptr, OPTBS, 0, 0, 0};
    P.nblk = 2; P.act = 2; P.W = gateH; P.bias = gate_b;
    P.e0 = OPTH; P.e0bs = LLBS; P.e1 = buf1; P.e1bs = OPTBS;
    P.out = buf2; P.outbs = OPTBS;
    fc_mfma_kernel<<<512, 256, 0, stream>>>(P);
  }

  // ---- stage C: doc attention ----
  rowdot_kernel<<<2048, 256, 0, stream>>>(buf2, OPTBS, 256, dw1, ql_c);
  rowdot_kernel<<<6144, 256, 0, stream>>>(lastH, LLBS, 768, dw2, kl_c);
  mm_at_kernel<1, 1, 0><<<dim3(6, 2, 32), 256, 0, stream>>>(buf2, OPTBS, HDIM, lastH, LLBS, HDIM, HDIM,
                                                            dw3, ql_c, 256, kl_c, 768, L, 196608, 768);
  softmax_cols_kernel<<<dim3(3, 32), 256, 0, stream>>>(L, kqC, 256, 768);
  softmax_rows_kernel<12><<<8192 / 4, 256, 0, stream>>>(L, awC);
  mm_ab_kernel<<<dim3(8, 2, 32), 256, 0, stream>>>(awC, 196608, 768, lastH, LLBS, HDIM, 768,
                                                   buf1, OPTBS, HDIM);
  mm_at_kernel<0, 0, 1><<<dim3(2, 2, 32), 256, 0, stream>>>(awC, 196608, 768, kqC, 196608, 768, 768,
                                                            nullptr, nullptr, 0, nullptr, 0, co_wH, 65536, 256);
  mm_ab_kernel<<<dim3(8, 2, 32), 256, 0, stream>>>(co_wH, 65536, 256, buf2, OPTBS, HDIM, 256,
                                                   buf3, OPTBS, HDIM);

  // ---- stage D: fusion ----
  {
    FCArgs P = {};
    P.src[0] = {buf2, nullptr, OPTBS, 0, 0, 0};
    P.src[1] = {buf1, nullptr, OPTBS, 0, 0, 0};
    P.src[2] = {buf3, nullptr, OPTBS, 0, 0, 0};
    P.nblk = 3; P.act = 1; P.W = attnH; P.bias = attn_b;
    P.out = buf4; P.outbs = OPTBS;
    fc_mfma_kernel<<<512, 256, 0, stream>>>(P);
  }

  // ---- stage E: self-attention ----
  rowdot_kernel<<<2048, 256, 0, stream>>>(buf4, OPTBS, 256, sw1, ql_e);
  rowdot_kernel<<<2048, 256, 0, stream>>>(buf4, OPTBS, 256, sw2, kl_e);
  mm_at_kernel<1, 1, 0><<<dim3(2, 2, 32), 256, 0, stream>>>(buf4, OPTBS, HDIM, buf4, OPTBS, HDIM, HDIM,
                                                            sw3, ql_e, 256, kl_e, 256, L, 65536, 256);
  softmax_rows_kernel<4><<<8192 / 4, 256, 0, stream>>>(L, pE);
  mm_ab_kernel<<<dim3(8, 2, 32), 256, 0, stream>>>(pE, 65536, 256, buf4, OPTBS, HDIM, 256,
                                                   buf2, OPTBS, HDIM);

  // ---- stage F: fusion2 ----
  {
    FCArgs P = {};
    P.src[0] = {buf4, nullptr, OPTBS, 0, 0, 0};
    P.src[1] = {buf2, nullptr, OPTBS, 0, 0, 0};
    P.src[2] = {buf4, buf2, OPTBS, OPTBS, 1, 0};
    P.src[3] = {buf4, buf2, OPTBS, OPTBS, 2, 0};
    P.nblk = 4; P.act = 1; P.W = selfH; P.bias = self_b;
    P.out = buf3; P.outbs = OPTBS;
    fc_mfma_kernel<<<512, 256, 0, stream>>>(P);
  }

  // ---- stage G ----
  colmax_kernel<<<dim3(4, 32), 256, 0, stream>>>(buf3, (float*)d_out);
}